// Round 2
// baseline (454.970 us; speedup 1.0000x reference)
//
#include <hip/hip_runtime.h>
#include <hip/hip_fp16.h>

static constexpr float FILLW = 2.0f;
static constexpr int BSH  = 6;      // 64 nodes per coarse bucket
static constexpr int CAPB = 1792;   // bucket capacity (mean 1024, sd ~32 -> 24 sigma)
static constexpr int NPB  = 128;    // partition blocks per tower

// ======================= register-blocked GEMM tile =======================
template<int F, int K, int TR, int KC, bool SCALE, typename OutT>
__device__ __forceinline__ void gemm_tile(const float* __restrict__ A,
        const float* __restrict__ W, OutT* __restrict__ C,
        const float* __restrict__ dv, int rb, int N,
        float* __restrict__ Ws, float* __restrict__ As){
    constexpr int NCH = K / KC;
    constexpr int TRp = TR + 4;
    constexpr int CG  = F / 8;
    constexpr int LPT = TR * KC / 1024;
    const int tid = threadIdx.x;
    for (int i = tid; i < K * F / 4; i += 256)
        ((float4*)Ws)[i] = ((const float4*)W)[i];
    const int tx = tid % CG, ty = tid / CG;
    const int c0 = tx * 8, r0 = ty * 8;

    float acc[8][8];
    #pragma unroll
    for (int i = 0; i < 8; ++i)
        #pragma unroll
        for (int j = 0; j < 8; ++j) acc[i][j] = 0.f;

    float4 st[LPT];
    auto gload = [&](int kc){
        #pragma unroll
        for (int l2 = 0; l2 < LPT; ++l2){
            int l = l2 * 256 + tid;
            int r = l / (KC / 4);
            int kk = (l % (KC / 4)) * 4;
            int ar = rb + r; if (ar >= N) ar = N - 1;
            st[l2] = *(const float4*)(A + (size_t)ar * K + kc * KC + kk);
        }
    };
    auto swrite = [&](int buf){
        float* p = As + buf * (KC * TRp);
        #pragma unroll
        for (int l2 = 0; l2 < LPT; ++l2){
            int l = l2 * 256 + tid;
            int r = l / (KC / 4);
            int kk = (l % (KC / 4)) * 4;
            p[(kk+0)*TRp + r] = st[l2].x;
            p[(kk+1)*TRp + r] = st[l2].y;
            p[(kk+2)*TRp + r] = st[l2].z;
            p[(kk+3)*TRp + r] = st[l2].w;
        }
    };

    gload(0); swrite(0);
    __syncthreads();
    for (int kc = 0; kc < NCH; ++kc){
        if (kc + 1 < NCH) gload(kc + 1);
        const float* Ab = As + (kc & 1) * (KC * TRp);
        #pragma unroll
        for (int j = 0; j < KC; ++j){
            const float* wrow = Ws + (kc * KC + j) * F + c0;
            float4 w0 = *(const float4*)(wrow);
            float4 w1 = *(const float4*)(wrow + 4);
            float4 a0 = *(const float4*)(Ab + j * TRp + r0);
            float4 a1 = *(const float4*)(Ab + j * TRp + r0 + 4);
            float av[8] = {a0.x,a0.y,a0.z,a0.w,a1.x,a1.y,a1.z,a1.w};
            float wvv[8] = {w0.x,w0.y,w0.z,w0.w,w1.x,w1.y,w1.z,w1.w};
            #pragma unroll
            for (int rr = 0; rr < 8; ++rr)
                #pragma unroll
                for (int cc = 0; cc < 8; ++cc)
                    acc[rr][cc] = fmaf(av[rr], wvv[cc], acc[rr][cc]);
        }
        if (kc + 1 < NCH){ swrite((kc + 1) & 1); __syncthreads(); }
    }
    #pragma unroll
    for (int rr = 0; rr < 8; ++rr){
        int row = rb + r0 + rr;
        if (row < N){
            float scv = 1.0f;
            if constexpr (SCALE) scv = dv[row];
            if constexpr (sizeof(OutT) == 2){
                __half2 o2[4];
                #pragma unroll
                for (int q = 0; q < 4; ++q)
                    o2[q] = __floats2half2_rn(acc[rr][2*q]*scv, acc[rr][2*q+1]*scv);
                *(float4*)((__half*)C + (size_t)row * F + c0) = *(float4*)o2;
            } else {
                float4 o0 = {acc[rr][0]*scv, acc[rr][1]*scv, acc[rr][2]*scv, acc[rr][3]*scv};
                float4 o1 = {acc[rr][4]*scv, acc[rr][5]*scv, acc[rr][6]*scv, acc[rr][7]*scv};
                *(float4*)((float*)C + (size_t)row * F + c0)     = o0;
                *(float4*)((float*)C + (size_t)row * F + c0 + 4) = o1;
            }
        }
    }
}

// ===== fused: GEMM1 (fp16 out) + coarse-bucket partition of edges =====
// Partition blocks: LDS histogram over B1 buckets (64 nodes each), ONE global
// atomicAdd per (block,bucket) to reserve space (~100k atomics vs 1.6M), then
// scatter packed 8B records at LDS-atomic ranks. All per-edge atomics are LDS.
__global__ void __launch_bounds__(256) k_cg1(const float* __restrict__ x,
        const float* __restrict__ W1, __half* __restrict__ h1,
        const int* __restrict__ src, const int* __restrict__ dst,
        const float* __restrict__ ew,
        uint2* __restrict__ stage, int* __restrict__ gcnt,
        int N, int E, int BPT, int B1){
    __shared__ float Ws[64 * 128];
    __shared__ float As[2 * 8 * 260];
    if ((int)blockIdx.x < BPT){
        int rb = (int)blockIdx.x * 256;
        gemm_tile<64,128,256,8,false,__half>(x, W1, h1, nullptr, rb, N, Ws, As);
        return;
    }
    int blk = (int)blockIdx.x - BPT;
    int* hist = (int*)Ws;                 // B1 ints, aliases GEMM's W tile
    const int tid = threadIdx.x;
    for (int i = tid; i < B1; i += 256) hist[i] = 0;
    __syncthreads();
    int per = (E + NPB - 1) / NPB;
    int e0 = blk * per;
    int e1 = e0 + per; if (e1 > E) e1 = E;
    for (int e = e0 + tid; e < e1; e += 256)
        atomicAdd(&hist[dst[e] >> BSH], 1);
    __syncthreads();
    // reserve: rotate start bucket per block to spread same-address contention
    int rot = (blk * 193) % B1;
    for (int i = tid; i < B1; i += 256){
        int b = i + rot; if (b >= B1) b -= B1;
        int h = hist[b];
        hist[b] = h ? atomicAdd(&gcnt[b], h) : 0;
    }
    __syncthreads();
    for (int e = e0 + tid; e < e1; e += 256){
        int d = dst[e];
        int b = d >> BSH;
        float w = fmaxf(ew[e], 0.f);
        int r = atomicAdd(&hist[b], 1);   // LDS: reserved base + local rank
        if (r < CAPB)
            stage[(size_t)b * CAPB + r] =
                make_uint2(__float_as_uint(w),
                           (unsigned)src[e] | ((unsigned)(d & 63) << 16));
    }
}

// ===== pack: per-bucket 64-bin count+scan -> woff, sn (CSR), dinv =====
__global__ void __launch_bounds__(256) k_pack(const uint2* __restrict__ stage,
        const int* __restrict__ gcnt, int* __restrict__ woff,
        float2* __restrict__ sn, float* __restrict__ dinv, int N, int B1){
    const int b = (int)blockIdx.x, tid = threadIdx.x;
    __shared__ int   wsum[4];
    __shared__ int   nh[64];
    __shared__ float nw[64];
    __shared__ int   offs[64];
    // exclusive bucket base = sum gcnt[0..b)
    int acc = 0;
    for (int i = tid; i < b; i += 256) acc += gcnt[i];
    #pragma unroll
    for (int o = 32; o; o >>= 1) acc += __shfl_down(acc, o);
    int lane = tid & 63, wv = tid >> 6;
    if (lane == 0) wsum[wv] = acc;
    if (tid < 64){ nh[tid] = 0; nw[tid] = 0.f; }
    __syncthreads();
    const int base = wsum[0] + wsum[1] + wsum[2] + wsum[3];
    int cnt = gcnt[b]; if (cnt > CAPB) cnt = CAPB;

    int   rr[7]; uint2 rec[7];
    #pragma unroll
    for (int q = 0; q < 7; ++q){
        int j = q * 256 + tid;
        if (j < cnt){
            uint2 v = stage[(size_t)b * CAPB + j];
            int nl = (v.y >> 16) & 63;
            rr[q] = atomicAdd(&nh[nl], 1);
            atomicAdd(&nw[nl], __uint_as_float(v.x));
            rec[q] = v;
        } else rec[q].y = 0xFFFFFFFFu;     // real records have bits 22..31 == 0
    }
    __syncthreads();
    if (tid < 64){
        int v = nh[tid], sc = v;
        #pragma unroll
        for (int o = 1; o < 64; o <<= 1){ int u = __shfl_up(sc, o); if (tid >= o) sc += u; }
        offs[tid] = sc - v;                // exclusive within-bucket prefix
        int n = (b << BSH) + tid;
        if (n < N){
            woff[n] = base + sc - v;
            dinv[n] = rsqrtf(FILLW + nw[tid]);
        }
    }
    __syncthreads();
    #pragma unroll
    for (int q = 0; q < 7; ++q){
        if (rec[q].y != 0xFFFFFFFFu){
            int nl   = (int)((rec[q].y >> 16) & 63);
            int srcv = (int)(rec[q].y & 0xFFFFu);
            sn[(size_t)base + offs[nl] + rr[q]] =
                make_float2(__int_as_float(srcv), __uint_as_float(rec[q].x));
        }
    }
}

// ===== prescale h1 rows by dinv (fp16 in place) =====
__global__ void __launch_bounds__(256) k_prescale(const float* __restrict__ dinv,
        __half* __restrict__ h1, int N){
    int g = (int)blockIdx.x * 256 + threadIdx.x;
    float dv = (g < N) ? dinv[g] : 0.f;
    int lane  = threadIdx.x & 63;
    int wbase = (int)blockIdx.x * 256 + (threadIdx.x & ~63);
    for (int r = 0; r < 64; ++r){
        int gr = wbase + r;
        float scv = __shfl(dv, r);
        if (gr < N){
            __half* row = h1 + (size_t)gr * 64;
            row[lane] = __float2half(__half2float(row[lane]) * scv);
        }
    }
}

// ================== GEMM2: fp32 in, dinv-prescaled fp16 out ==================
__global__ void __launch_bounds__(256) k_gemm2(const float* __restrict__ A,
        const float* __restrict__ W, __half* __restrict__ C,
        const float* __restrict__ dinv, int N){
    __shared__ float Ws[64 * 128];
    __shared__ float As[2 * 16 * 132];
    int rb = (int)blockIdx.x * 128;
    gemm_tile<128,64,128,16,true,__half>(A, W, C, dinv, rb, N, Ws, As);
}

// ===== CSR gather-max: coalesced edge-record load + shfl broadcast + deep unroll =====
template<int F, int V, int UNR>   // V = F/64 values per lane
__global__ void __launch_bounds__(256) k_agg(const int* __restrict__ woff,
        const float2* __restrict__ sn, const float* __restrict__ dinv,
        const __half* __restrict__ H, const float* __restrict__ bias,
        float* __restrict__ O, int N, int E){
    const int lane = threadIdx.x & 63, wv = threadIdx.x >> 6;
    int n = (int)blockIdx.x * 4 + wv;
    if (n >= N) return;
    int beg = woff[n];
    int end = (n == N - 1) ? E : woff[n + 1];
    int cnt = end - beg;
    float di = dinv[n];
    float v0, v1 = 0.f;
    if (V == 1) {
        v0 = FILLW * __half2float(H[(size_t)n * F + lane]);
    } else {
        float2 h = __half22float2(((const __half2*)H)[(size_t)n * (F/2) + lane]);
        v0 = FILLW * h.x; v1 = FILLW * h.y;
    }
    for (int base = 0; base < cnt; base += 64){
        int m = cnt - base; if (m > 64) m = 64;
        float2 er = make_float2(0.f, 0.f);
        if (lane < m) er = sn[beg + base + lane];     // ONE coalesced load: 64 records
        int   es = __float_as_int(er.x);
        float ew = er.y;
        int j = 0;
        for (; j + UNR <= m; j += UNR){
            int ss[UNR]; float ww[UNR];
            #pragma unroll
            for (int q = 0; q < UNR; ++q){ ss[q] = __shfl(es, j + q); ww[q] = __shfl(ew, j + q); }
            if (V == 1){
                float hh[UNR];
                #pragma unroll
                for (int q = 0; q < UNR; ++q)
                    hh[q] = __half2float(H[(size_t)ss[q] * F + lane]);   // UNR independent gathers
                #pragma unroll
                for (int q = 0; q < UNR; ++q) v0 = fmaxf(v0, ww[q] * hh[q]);
            } else {
                float2 hh[UNR];
                #pragma unroll
                for (int q = 0; q < UNR; ++q)
                    hh[q] = __half22float2(((const __half2*)H)[(size_t)ss[q] * (F/2) + lane]);
                #pragma unroll
                for (int q = 0; q < UNR; ++q){
                    v0 = fmaxf(v0, ww[q] * hh[q].x);
                    v1 = fmaxf(v1, ww[q] * hh[q].y);
                }
            }
        }
        for (; j < m; ++j){
            int s = __shfl(es, j); float w = __shfl(ew, j);
            if (V == 1){
                v0 = fmaxf(v0, w * __half2float(H[(size_t)s * F + lane]));
            } else {
                float2 h = __half22float2(((const __half2*)H)[(size_t)s * (F/2) + lane]);
                v0 = fmaxf(v0, w * h.x); v1 = fmaxf(v1, w * h.y);
            }
        }
    }
    if (V == 1) {
        O[(size_t)n * F + lane] = di * v0 + bias[lane];
    } else {
        float2 bb = ((const float2*)bias)[lane];
        ((float2*)O)[(size_t)n * (F/2) + lane] = make_float2(di*v0 + bb.x, di*v1 + bb.y);
    }
}

// ============================== host ==============================

extern "C" void kernel_launch(void* const* d_in, const int* in_sizes, int n_in,
                              void* d_out, int out_size, void* d_ws, size_t ws_size,
                              hipStream_t stream){
    const int E  = in_sizes[2];        // 800000
    const int F1 = in_sizes[7];        // 64
    const int F2 = in_sizes[9];        // 128
    const int IN = in_sizes[6] / F1;   // 128
    const int N  = in_sizes[0] / IN;   // 50000 (must be < 65536 for 8B staging records)
    const int B1 = (N + 63) >> BSH;    // 782 coarse buckets

    const float* W1 = (const float*)d_in[6];
    const float* b1 = (const float*)d_in[7];
    const float* W2 = (const float*)d_in[8];
    const float* b2 = (const float*)d_in[9];

    // workspace layout (~32.4 MB):
    //   sn    : E float2           (CSR edge records)
    //   hbuf  : N*F2 halves        (h1 in first N*F1, h2 full)
    //   out1  : N*F1 floats        -- aliased by stage (B1*CAPB uint2, 11.2MB <= 12.8MB)
    //   dinv  : N floats
    //   woff  : N ints
    //   gcnt  : B1 ints
    float2* sn    = (float2*)d_ws;
    __half* hbuf  = (__half*)(sn + (size_t)E);
    float*  out1  = (float*)(hbuf + (size_t)N * F2);
    uint2*  stage = (uint2*)out1;
    float*  dinv  = out1 + (size_t)N * F1;
    int*    woff  = (int*)(dinv + N);
    int*    gcnt  = woff + N;

    const int BPT1 = (N + 255) / 256;
    const int BPT2 = (N + 127) / 128;
    const int ABT  = (N + 3) / 4;

    for (int t = 0; t < 2; ++t){
        const float* x  = (const float*)d_in[t*3];
        const int*   ei = (const int*)  d_in[t*3+1];
        const float* ew = (const float*)d_in[t*3+2];
        const int* src = ei, * dst = ei + E;
        float* go = (float*)d_out + (size_t)t * N * F2;

        hipMemsetAsync(gcnt, 0, (size_t)B1 * sizeof(int), stream);
        k_cg1<<<BPT1 + NPB, 256, 0, stream>>>(x, W1, hbuf, src, dst, ew,
                                              stage, gcnt, N, E, BPT1, B1);
        k_pack<<<B1, 256, 0, stream>>>(stage, gcnt, woff, sn, dinv, N, B1);
        k_prescale<<<(N + 255) / 256, 256, 0, stream>>>(dinv, hbuf, N);
        k_agg<64,1,8><<<ABT, 256, 0, stream>>>(woff, sn, dinv, hbuf, b1, out1, N, E);
        k_gemm2<<<BPT2, 256, 0, stream>>>(out1, W2, hbuf, dinv, N);
        k_agg<128,2,8><<<ABT, 256, 0, stream>>>(woff, sn, dinv, hbuf, b2, go, N, E);
    }
}

// Round 3
// 357.420 us; speedup vs baseline: 1.2729x; 1.2729x over previous
//
#include <hip/hip_runtime.h>
#include <hip/hip_fp16.h>

static constexpr float FILLW = 2.0f;
static constexpr int BSH  = 6;      // 64 nodes per coarse bucket
static constexpr int CAPB = 1792;   // bucket capacity (mean 1024, sd ~32 -> 24 sigma)
static constexpr int NPB  = 128;    // partition blocks per tower
static constexpr int EPT  = 8;      // partition edges/thread batch (ILP)

// ======================= register-blocked GEMM tile =======================
template<int F, int K, int TR, int KC, bool SCALE, typename OutT>
__device__ __forceinline__ void gemm_tile(const float* __restrict__ A,
        const float* __restrict__ W, OutT* __restrict__ C,
        const float* __restrict__ dv, int rb, int N,
        float* __restrict__ Ws, float* __restrict__ As){
    constexpr int NCH = K / KC;
    constexpr int TRp = TR + 4;
    constexpr int CG  = F / 8;
    constexpr int LPT = TR * KC / 1024;
    const int tid = threadIdx.x;
    for (int i = tid; i < K * F / 4; i += 256)
        ((float4*)Ws)[i] = ((const float4*)W)[i];
    const int tx = tid % CG, ty = tid / CG;
    const int c0 = tx * 8, r0 = ty * 8;

    float acc[8][8];
    #pragma unroll
    for (int i = 0; i < 8; ++i)
        #pragma unroll
        for (int j = 0; j < 8; ++j) acc[i][j] = 0.f;

    float4 st[LPT];
    auto gload = [&](int kc){
        #pragma unroll
        for (int l2 = 0; l2 < LPT; ++l2){
            int l = l2 * 256 + tid;
            int r = l / (KC / 4);
            int kk = (l % (KC / 4)) * 4;
            int ar = rb + r; if (ar >= N) ar = N - 1;
            st[l2] = *(const float4*)(A + (size_t)ar * K + kc * KC + kk);
        }
    };
    auto swrite = [&](int buf){
        float* p = As + buf * (KC * TRp);
        #pragma unroll
        for (int l2 = 0; l2 < LPT; ++l2){
            int l = l2 * 256 + tid;
            int r = l / (KC / 4);
            int kk = (l % (KC / 4)) * 4;
            p[(kk+0)*TRp + r] = st[l2].x;
            p[(kk+1)*TRp + r] = st[l2].y;
            p[(kk+2)*TRp + r] = st[l2].z;
            p[(kk+3)*TRp + r] = st[l2].w;
        }
    };

    gload(0); swrite(0);
    __syncthreads();
    for (int kc = 0; kc < NCH; ++kc){
        if (kc + 1 < NCH) gload(kc + 1);
        const float* Ab = As + (kc & 1) * (KC * TRp);
        #pragma unroll
        for (int j = 0; j < KC; ++j){
            const float* wrow = Ws + (kc * KC + j) * F + c0;
            float4 w0 = *(const float4*)(wrow);
            float4 w1 = *(const float4*)(wrow + 4);
            float4 a0 = *(const float4*)(Ab + j * TRp + r0);
            float4 a1 = *(const float4*)(Ab + j * TRp + r0 + 4);
            float av[8] = {a0.x,a0.y,a0.z,a0.w,a1.x,a1.y,a1.z,a1.w};
            float wvv[8] = {w0.x,w0.y,w0.z,w0.w,w1.x,w1.y,w1.z,w1.w};
            #pragma unroll
            for (int rr = 0; rr < 8; ++rr)
                #pragma unroll
                for (int cc = 0; cc < 8; ++cc)
                    acc[rr][cc] = fmaf(av[rr], wvv[cc], acc[rr][cc]);
        }
        if (kc + 1 < NCH){ swrite((kc + 1) & 1); __syncthreads(); }
    }
    #pragma unroll
    for (int rr = 0; rr < 8; ++rr){
        int row = rb + r0 + rr;
        if (row < N){
            float scv = 1.0f;
            if constexpr (SCALE) scv = dv[row];
            if constexpr (sizeof(OutT) == 2){
                __half2 o2[4];
                #pragma unroll
                for (int q = 0; q < 4; ++q)
                    o2[q] = __floats2half2_rn(acc[rr][2*q]*scv, acc[rr][2*q+1]*scv);
                *(float4*)((__half*)C + (size_t)row * F + c0) = *(float4*)o2;
            } else {
                float4 o0 = {acc[rr][0]*scv, acc[rr][1]*scv, acc[rr][2]*scv, acc[rr][3]*scv};
                float4 o1 = {acc[rr][4]*scv, acc[rr][5]*scv, acc[rr][6]*scv, acc[rr][7]*scv};
                *(float4*)((float*)C + (size_t)row * F + c0)     = o0;
                *(float4*)((float*)C + (size_t)row * F + c0 + 4) = o1;
            }
        }
    }
}

// ===== fused: GEMM1 (fp16 out, both towers) + coarse-bucket edge partition =====
__global__ void __launch_bounds__(256) k_cg1(const float* __restrict__ x0,
        const float* __restrict__ x1, const float* __restrict__ W1,
        __half* __restrict__ h0, __half* __restrict__ h1,
        const int* __restrict__ src0, const int* __restrict__ src1,
        const int* __restrict__ dst0, const int* __restrict__ dst1,
        const float* __restrict__ ew0, const float* __restrict__ ew1,
        uint2* __restrict__ stage, int* __restrict__ gcnt,
        int N, int E, int BPT, int GB, int B1){
    __shared__ float Ws[64 * 128];
    __shared__ float As[2 * 8 * 260];
    if ((int)blockIdx.x < GB){
        int t  = (int)blockIdx.x / BPT;
        int rb = ((int)blockIdx.x - t * BPT) * 256;
        gemm_tile<64,128,256,8,false,__half>(t ? x1 : x0, W1, t ? h1 : h0,
                                             nullptr, rb, N, Ws, As);
        return;
    }
    int c = (int)blockIdx.x - GB;
    int t = c / NPB, blk = c % NPB;
    const int* src = t ? src1 : src0;
    const int* dst = t ? dst1 : dst0;
    const float* ew = t ? ew1 : ew0;
    uint2* stg = stage + (size_t)t * B1 * CAPB;
    int* gc = gcnt + t * B1;
    int* hist = (int*)Ws;                 // B1 ints, aliases GEMM's W tile
    const int tid = threadIdx.x;
    for (int i = tid; i < B1; i += 256) hist[i] = 0;
    __syncthreads();
    int per = (E + NPB - 1) / NPB;
    int e0 = blk * per;
    int e1 = e0 + per; if (e1 > E) e1 = E;
    // pass 1: LDS histogram, 8-batched for ILP
    for (int e = e0 + tid; e < e1; e += 256 * EPT){
        int dl[EPT];
        #pragma unroll
        for (int q = 0; q < EPT; ++q){ int ee = e + q*256; dl[q] = (ee < e1) ? dst[ee] : -1; }
        #pragma unroll
        for (int q = 0; q < EPT; ++q) if (dl[q] >= 0) atomicAdd(&hist[dl[q] >> BSH], 1);
    }
    __syncthreads();
    // reserve: rotate start bucket per block to spread same-address contention
    int rot = (blk * 193) % B1;
    for (int i = tid; i < B1; i += 256){
        int b = i + rot; if (b >= B1) b -= B1;
        int h = hist[b];
        hist[b] = h ? atomicAdd(&gc[b], h) : 0;
    }
    __syncthreads();
    // pass 2: scatter packed records at LDS-atomic ranks, 8-batched
    for (int e = e0 + tid; e < e1; e += 256 * EPT){
        int dl[EPT], sl[EPT]; float wl[EPT];
        #pragma unroll
        for (int q = 0; q < EPT; ++q){
            int ee = e + q*256;
            if (ee < e1){ dl[q] = dst[ee]; sl[q] = src[ee]; wl[q] = fmaxf(ew[ee], 0.f); }
            else dl[q] = -1;
        }
        int r[EPT];
        #pragma unroll
        for (int q = 0; q < EPT; ++q)
            if (dl[q] >= 0) r[q] = atomicAdd(&hist[dl[q] >> BSH], 1);
        #pragma unroll
        for (int q = 0; q < EPT; ++q)
            if (dl[q] >= 0 && r[q] < CAPB)
                stg[(size_t)(dl[q] >> BSH) * CAPB + r[q]] =
                    make_uint2(__float_as_uint(wl[q]),
                               (unsigned)sl[q] | ((unsigned)(dl[q] & 63) << 16));
    }
}

// ===== pack: per-bucket 64-bin count+scan -> woff, sn (CSR), dinv =====
__global__ void __launch_bounds__(256) k_pack(const uint2* __restrict__ stage,
        const int* __restrict__ gcnt, int* __restrict__ woff,
        float2* __restrict__ sn, float* __restrict__ dinv, int N, int E, int B1){
    const int bid = (int)blockIdx.x, tid = threadIdx.x;
    const int t = bid / B1, b = bid % B1;
    const uint2* stg = stage + (size_t)t * B1 * CAPB;
    const int* gc = gcnt + t * B1;
    __shared__ int   wsum[4];
    __shared__ int   nh[64];
    __shared__ float nw[64];
    __shared__ int   offs[64];
    // exclusive bucket base = sum gc[0..b)
    int acc = 0;
    for (int i = tid; i < b; i += 256) acc += gc[i];
    #pragma unroll
    for (int o = 32; o; o >>= 1) acc += __shfl_down(acc, o);
    int lane = tid & 63, wv = tid >> 6;
    if (lane == 0) wsum[wv] = acc;
    if (tid < 64){ nh[tid] = 0; nw[tid] = 0.f; }
    __syncthreads();
    const int base = wsum[0] + wsum[1] + wsum[2] + wsum[3];
    int cnt = gc[b]; if (cnt > CAPB) cnt = CAPB;

    int   rr[7]; uint2 rec[7];
    #pragma unroll
    for (int q = 0; q < 7; ++q){
        int j = q * 256 + tid;
        if (j < cnt){
            uint2 v = stg[(size_t)b * CAPB + j];
            int nl = (v.y >> 16) & 63;
            rr[q] = atomicAdd(&nh[nl], 1);
            atomicAdd(&nw[nl], __uint_as_float(v.x));
            rec[q] = v;
        } else rec[q].y = 0xFFFFFFFFu;     // real records have bits 22..31 == 0
    }
    __syncthreads();
    if (tid < 64){
        int v = nh[tid], sc = v;
        #pragma unroll
        for (int o = 1; o < 64; o <<= 1){ int u = __shfl_up(sc, o); if (tid >= o) sc += u; }
        offs[tid] = sc - v;                // exclusive within-bucket prefix
        int n = (b << BSH) + tid;
        if (n < N){
            woff[t * N + n] = base + sc - v;
            dinv[t * N + n] = rsqrtf(FILLW + nw[tid]);
        }
    }
    __syncthreads();
    float2* sno = sn + (size_t)t * E;
    #pragma unroll
    for (int q = 0; q < 7; ++q){
        if (rec[q].y != 0xFFFFFFFFu){
            int nl   = (int)((rec[q].y >> 16) & 63);
            int srcv = (int)(rec[q].y & 0xFFFFu);
            sno[(size_t)base + offs[nl] + rr[q]] =
                make_float2(__int_as_float(srcv), __uint_as_float(rec[q].x));
        }
    }
}

// ===== prescale h1 rows by dinv (fp16 in place, both towers contiguous) =====
__global__ void __launch_bounds__(256) k_prescale(const float* __restrict__ dinv,
        __half* __restrict__ h1, int GN){
    int g = (int)blockIdx.x * 256 + threadIdx.x;
    float dv = (g < GN) ? dinv[g] : 0.f;
    int lane  = threadIdx.x & 63;
    int wbase = (int)blockIdx.x * 256 + (threadIdx.x & ~63);
    for (int r = 0; r < 64; ++r){
        int gr = wbase + r;
        float scv = __shfl(dv, r);
        if (gr < GN){
            __half* row = h1 + (size_t)gr * 64;
            row[lane] = __float2half(__half2float(row[lane]) * scv);
        }
    }
}

// ================== GEMM2: fp32 in, dinv-prescaled fp16 out ==================
__global__ void __launch_bounds__(256) k_gemm2(const float* __restrict__ A0,
        const float* __restrict__ A1, const float* __restrict__ W,
        __half* __restrict__ C0, __half* __restrict__ C1,
        const float* __restrict__ dinv, int N, int BPT){
    __shared__ float Ws[64 * 128];
    __shared__ float As[2 * 16 * 132];
    int t  = (int)blockIdx.x / BPT;
    int rb = ((int)blockIdx.x - t * BPT) * 128;
    gemm_tile<128,64,128,16,true,__half>(t ? A1 : A0, W, t ? C1 : C0,
                                         dinv + t * N, rb, N, Ws, As);
}

// ===== CSR gather-max, grouped-row geometry =====
// LPR = F/8 lanes cooperate on one row (16B/lane); EG = 64/LPR rows gathered
// per wave-load; UG groups unrolled -> EG*UG rows in flight. Out-of-range
// slots clamp to edge m-1 (idempotent under max -> no tail loop).
template<int F, int UG>
__global__ void __launch_bounds__(256) k_agg(const int* __restrict__ woff,
        const float2* __restrict__ sn, const float* __restrict__ dinv,
        const __half* __restrict__ H0, const __half* __restrict__ H1,
        const float* __restrict__ bias, float* __restrict__ O0, float* __restrict__ O1,
        int N, int E, int BPT){
    constexpr int LPR = F / 8;        // lanes per row
    constexpr int EG  = 64 / LPR;     // edges per group
    const int t = (int)blockIdx.x / BPT;
    const int lane = threadIdx.x & 63, wv = threadIdx.x >> 6;
    int n = ((int)blockIdx.x - t * BPT) * 4 + wv;
    if (n >= N) return;
    int g = t * N + n;
    int beg = woff[g];
    int end = (n == N - 1) ? E : woff[g + 1];
    int cnt = end - beg;
    const float2* st = sn + (size_t)t * E;
    const __half* H = t ? H1 : H0;
    float* O = t ? O1 : O0;
    const int fl = lane % LPR;
    const int eg = lane / LPR;

    float acc[8];
    {
        float4 hv = *(const float4*)(H + (size_t)n * F + fl * 8);
        const __half2* hp = (const __half2*)&hv;
        #pragma unroll
        for (int k = 0; k < 4; ++k){
            float2 f = __half22float2(hp[k]);
            acc[2*k]   = FILLW * f.x;
            acc[2*k+1] = FILLW * f.y;
        }
    }
    for (int base = 0; base < cnt; base += 64){
        int m = cnt - base; if (m > 64) m = 64;
        float2 er = make_float2(0.f, 0.f);
        if (lane < m) er = st[beg + base + lane];     // ONE coalesced load: 64 records
        int   es = __float_as_int(er.x);
        float ew = er.y;
        for (int j = 0; j < m; j += EG * UG){
            int sl[UG]; float wl[UG]; float4 hv[UG];
            #pragma unroll
            for (int u = 0; u < UG; ++u){
                int jj = j + u * EG + eg; if (jj > m - 1) jj = m - 1;
                sl[u] = __shfl(es, jj);
                wl[u] = __shfl(ew, jj);
            }
            #pragma unroll
            for (int u = 0; u < UG; ++u)
                hv[u] = *(const float4*)(H + (size_t)sl[u] * F + fl * 8);
            #pragma unroll
            for (int u = 0; u < UG; ++u){
                const __half2* hp = (const __half2*)&hv[u];
                #pragma unroll
                for (int k = 0; k < 4; ++k){
                    float2 f = __half22float2(hp[k]);
                    acc[2*k]   = fmaxf(acc[2*k],   wl[u] * f.x);
                    acc[2*k+1] = fmaxf(acc[2*k+1], wl[u] * f.y);
                }
            }
        }
    }
    #pragma unroll
    for (int msk = LPR; msk < 64; msk <<= 1)
        #pragma unroll
        for (int k = 0; k < 8; ++k) acc[k] = fmaxf(acc[k], __shfl_xor(acc[k], msk));
    float di = dinv[g];
    if constexpr (F == 128){
        int f0 = fl * 8 + eg * 2;
        float2 bb = *(const float2*)(bias + f0);
        *(float2*)(O + (size_t)n * F + f0) =
            make_float2(di * acc[eg*2] + bb.x, di * acc[eg*2+1] + bb.y);
    } else {
        int f0 = fl * 8 + eg;
        O[(size_t)n * F + f0] = di * acc[eg] + bias[f0];
    }
}

// ============================== host ==============================

extern "C" void kernel_launch(void* const* d_in, const int* in_sizes, int n_in,
                              void* d_out, int out_size, void* d_ws, size_t ws_size,
                              hipStream_t stream){
    const int E  = in_sizes[2];        // 800000
    const int F1 = in_sizes[7];        // 64
    const int F2 = in_sizes[9];        // 128
    const int IN = in_sizes[6] / F1;   // 128
    const int N  = in_sizes[0] / IN;   // 50000 (< 65536 for 8B staging records)
    const int B1 = (N + 63) >> BSH;    // 782 coarse buckets

    const float* W1 = (const float*)d_in[6];
    const float* b1 = (const float*)d_in[7];
    const float* W2 = (const float*)d_in[8];
    const float* b2 = (const float*)d_in[9];

    auto need = [&](int G){
        return (size_t)G * E * 8              // sn
             + (size_t)G * N * F2 * 2         // hbuf (fp16)
             + (size_t)G * N * F1 * 4         // out1 (stage aliases: G*B1*CAPB*8 <= this)
             + (size_t)G * N * 8              // dinv + woff
             + (size_t)G * B1 * 4             // gcnt
             + 4096;
    };
    const int G = (ws_size >= need(2)) ? 2 : 1;

    float2* sn    = (float2*)d_ws;
    __half* hbuf  = (__half*)(sn + (size_t)G * E);
    float*  out1  = (float*)(hbuf + (size_t)G * N * F2);
    uint2*  stage = (uint2*)out1;              // G*B1*CAPB*8B = 22.4MB <= 25.6MB
    float*  dinv  = out1 + (size_t)G * N * F1;
    int*    woff  = (int*)(dinv + (size_t)G * N);
    int*    gcnt  = woff + (size_t)G * N;

    const int BPT1 = (N + 255) / 256;
    const int BPT2 = (N + 127) / 128;
    const int ABT  = (N + 3) / 4;
    const int GB   = G * BPT1;

    for (int it = 0; it < 2; it += G){
        int t0 = it, t1 = (G == 2) ? it + 1 : it;
        const float* x0 = (const float*)d_in[t0*3], * x1 = (const float*)d_in[t1*3];
        const int* ei0 = (const int*)d_in[t0*3+1], * ei1 = (const int*)d_in[t1*3+1];
        const float* ew0 = (const float*)d_in[t0*3+2], * ew1 = (const float*)d_in[t1*3+2];
        const int* src0 = ei0, * dst0 = ei0 + E;
        const int* src1 = ei1, * dst1 = ei1 + E;
        __half* h1_0 = hbuf, * h1_1 = hbuf + (size_t)(G-1) * N * F1;
        __half* h2_0 = hbuf, * h2_1 = hbuf + (size_t)(G-1) * N * F2;
        float* o1_0 = out1, * o1_1 = out1 + (size_t)(G-1) * N * F1;
        float* go0 = (float*)d_out + (size_t)t0 * N * F2;
        float* go1 = (float*)d_out + (size_t)t1 * N * F2;

        hipMemsetAsync(gcnt, 0, (size_t)G * B1 * sizeof(int), stream);
        k_cg1<<<GB + G * NPB, 256, 0, stream>>>(x0, x1, W1, h1_0, h1_1,
                                                src0, src1, dst0, dst1, ew0, ew1,
                                                stage, gcnt, N, E, BPT1, GB, B1);
        k_pack<<<G * B1, 256, 0, stream>>>(stage, gcnt, woff, sn, dinv, N, E, B1);
        k_prescale<<<(G * N + 255) / 256, 256, 0, stream>>>(dinv, hbuf, G * N);
        k_agg<64,2><<<G * ABT, 256, 0, stream>>>(woff, sn, dinv, h1_0, h1_1, b1,
                                                 o1_0, o1_1, N, E, ABT);
        k_gemm2<<<G * BPT2, 256, 0, stream>>>(o1_0, o1_1, W2, h2_0, h2_1, dinv, N, BPT2);
        k_agg<128,4><<<G * ABT, 256, 0, stream>>>(woff, sn, dinv, h2_0, h2_1, b2,
                                                  go0, go1, N, E, ABT);
    }
}

// Round 4
// 339.861 us; speedup vs baseline: 1.3387x; 1.0517x over previous
//
#include <hip/hip_runtime.h>
#include <hip/hip_fp16.h>

static constexpr float FILLW = 2.0f;
static constexpr int BSH  = 6;      // 64 nodes per coarse bucket
static constexpr int CAPB = 1792;   // bucket capacity (mean 1024, sd ~32 -> 24 sigma)
static constexpr int NPB  = 256;    // partition blocks per tower (scanR assumes 256)
static constexpr int EPT  = 8;      // partition edges/thread batch (ILP)

// packed f16 helpers (VOP3P); keep values as 32-bit words
__device__ __forceinline__ unsigned pk_mul(unsigned a, unsigned b){
    unsigned r; asm("v_pk_mul_f16 %0, %1, %2" : "=v"(r) : "v"(a), "v"(b)); return r;
}
__device__ __forceinline__ unsigned pk_max(unsigned a, unsigned b){
    unsigned r; asm("v_pk_max_f16 %0, %1, %2" : "=v"(r) : "v"(a), "v"(b)); return r;
}

// ======================= register-blocked GEMM tile =======================
template<int F, int K, int TR, int KC, bool SCALE, typename OutT>
__device__ __forceinline__ void gemm_tile(const float* __restrict__ A,
        const float* __restrict__ W, OutT* __restrict__ C,
        const float* __restrict__ dv, int rb, int N,
        float* __restrict__ Ws, float* __restrict__ As){
    constexpr int NCH = K / KC;
    constexpr int TRp = TR + 4;
    constexpr int CG  = F / 8;
    constexpr int LPT = TR * KC / 1024;
    const int tid = threadIdx.x;
    for (int i = tid; i < K * F / 4; i += 256)
        ((float4*)Ws)[i] = ((const float4*)W)[i];
    const int tx = tid % CG, ty = tid / CG;
    const int c0 = tx * 8, r0 = ty * 8;

    float acc[8][8];
    #pragma unroll
    for (int i = 0; i < 8; ++i)
        #pragma unroll
        for (int j = 0; j < 8; ++j) acc[i][j] = 0.f;

    float4 st[LPT];
    auto gload = [&](int kc){
        #pragma unroll
        for (int l2 = 0; l2 < LPT; ++l2){
            int l = l2 * 256 + tid;
            int r = l / (KC / 4);
            int kk = (l % (KC / 4)) * 4;
            int ar = rb + r; if (ar >= N) ar = N - 1;
            st[l2] = *(const float4*)(A + (size_t)ar * K + kc * KC + kk);
        }
    };
    auto swrite = [&](int buf){
        float* p = As + buf * (KC * TRp);
        #pragma unroll
        for (int l2 = 0; l2 < LPT; ++l2){
            int l = l2 * 256 + tid;
            int r = l / (KC / 4);
            int kk = (l % (KC / 4)) * 4;
            p[(kk+0)*TRp + r] = st[l2].x;
            p[(kk+1)*TRp + r] = st[l2].y;
            p[(kk+2)*TRp + r] = st[l2].z;
            p[(kk+3)*TRp + r] = st[l2].w;
        }
    };

    gload(0); swrite(0);
    __syncthreads();
    for (int kc = 0; kc < NCH; ++kc){
        if (kc + 1 < NCH) gload(kc + 1);
        const float* Ab = As + (kc & 1) * (KC * TRp);
        #pragma unroll
        for (int j = 0; j < KC; ++j){
            const float* wrow = Ws + (kc * KC + j) * F + c0;
            float4 w0 = *(const float4*)(wrow);
            float4 w1 = *(const float4*)(wrow + 4);
            float4 a0 = *(const float4*)(Ab + j * TRp + r0);
            float4 a1 = *(const float4*)(Ab + j * TRp + r0 + 4);
            float av[8] = {a0.x,a0.y,a0.z,a0.w,a1.x,a1.y,a1.z,a1.w};
            float wvv[8] = {w0.x,w0.y,w0.z,w0.w,w1.x,w1.y,w1.z,w1.w};
            #pragma unroll
            for (int rr = 0; rr < 8; ++rr)
                #pragma unroll
                for (int cc = 0; cc < 8; ++cc)
                    acc[rr][cc] = fmaf(av[rr], wvv[cc], acc[rr][cc]);
        }
        if (kc + 1 < NCH){ swrite((kc + 1) & 1); __syncthreads(); }
    }
    #pragma unroll
    for (int rr = 0; rr < 8; ++rr){
        int row = rb + r0 + rr;
        if (row < N){
            float scv = 1.0f;
            if constexpr (SCALE) scv = dv[row];
            if constexpr (sizeof(OutT) == 2){
                __half2 o2[4];
                #pragma unroll
                for (int q = 0; q < 4; ++q)
                    o2[q] = __floats2half2_rn(acc[rr][2*q]*scv, acc[rr][2*q+1]*scv);
                *(float4*)((__half*)C + (size_t)row * F + c0) = *(float4*)o2;
            } else {
                float4 o0 = {acc[rr][0]*scv, acc[rr][1]*scv, acc[rr][2]*scv, acc[rr][3]*scv};
                float4 o1 = {acc[rr][4]*scv, acc[rr][5]*scv, acc[rr][6]*scv, acc[rr][7]*scv};
                *(float4*)((float*)C + (size_t)row * F + c0)     = o0;
                *(float4*)((float*)C + (size_t)row * F + c0 + 4) = o1;
            }
        }
    }
}

// ===== fused: GEMM1 (fp16 out, both towers) + per-(block,bucket) counts =====
// No global atomics: each partition block histograms its edge chunk in LDS and
// writes the B1 counts coalesced to cnts[t][blk][b].
__global__ void __launch_bounds__(256) k_cg1(const float* __restrict__ x0,
        const float* __restrict__ x1, const float* __restrict__ W1,
        __half* __restrict__ h0, __half* __restrict__ h1,
        const int* __restrict__ dst0, const int* __restrict__ dst1,
        int* __restrict__ cnts,
        int N, int E, int BPT, int GB, int B1){
    __shared__ float Ws[64 * 128];
    __shared__ float As[2 * 8 * 260];
    if ((int)blockIdx.x < GB){
        int t  = (int)blockIdx.x / BPT;
        int rb = ((int)blockIdx.x - t * BPT) * 256;
        gemm_tile<64,128,256,8,false,__half>(t ? x1 : x0, W1, t ? h1 : h0,
                                             nullptr, rb, N, Ws, As);
        return;
    }
    int c = (int)blockIdx.x - GB;
    int t = c / NPB, blk = c % NPB;
    const int* dst = t ? dst1 : dst0;
    int* hist = (int*)Ws;                 // B1 ints, aliases GEMM's W tile
    const int tid = threadIdx.x;
    for (int i = tid; i < B1; i += 256) hist[i] = 0;
    __syncthreads();
    int per = (E + NPB - 1) / NPB;
    int e0 = blk * per;
    int e1 = e0 + per; if (e1 > E) e1 = E;
    for (int e = e0 + tid; e < e1; e += 256 * EPT){
        int dl[EPT];
        #pragma unroll
        for (int q = 0; q < EPT; ++q){ int ee = e + q*256; dl[q] = (ee < e1) ? dst[ee] : -1; }
        #pragma unroll
        for (int q = 0; q < EPT; ++q) if (dl[q] >= 0) atomicAdd(&hist[dl[q] >> BSH], 1);
    }
    __syncthreads();
    int* co = cnts + (size_t)(t * NPB + blk) * B1;
    for (int i = tid; i < B1; i += 256) co[i] = hist[i];
}

// ===== scanR: per bucket, exclusive scan of NPB=256 block counts (in place) =====
__global__ void __launch_bounds__(64) k_scanR(int* __restrict__ cnts,
        int* __restrict__ gcnt, int B1){
    int bid = (int)blockIdx.x;
    int t = bid / B1, b = bid % B1;
    int lane = threadIdx.x;
    int* cp = cnts + (size_t)t * NPB * B1 + b;
    int x[4];
    #pragma unroll
    for (int j = 0; j < 4; ++j) x[j] = cp[(size_t)(lane * 4 + j) * B1];
    int s = x[0] + x[1] + x[2] + x[3];
    int sc = s;
    #pragma unroll
    for (int o = 1; o < 64; o <<= 1){ int u = __shfl_up(sc, o); if (lane >= o) sc += u; }
    int e0 = sc - s;
    int e1 = e0 + x[0], e2 = e1 + x[1], e3 = e2 + x[2];
    cp[(size_t)(lane * 4 + 0) * B1] = e0;
    cp[(size_t)(lane * 4 + 1) * B1] = e1;
    cp[(size_t)(lane * 4 + 2) * B1] = e2;
    cp[(size_t)(lane * 4 + 3) * B1] = e3;
    if (lane == 63) gcnt[t * B1 + b] = sc;
}

// ===== scatter: replay LDS ranks from scanned bases, write packed records =====
__global__ void __launch_bounds__(256) k_scatter(const int* __restrict__ src0,
        const int* __restrict__ src1,
        const int* __restrict__ dst0, const int* __restrict__ dst1,
        const float* __restrict__ ew0, const float* __restrict__ ew1,
        const int* __restrict__ cnts, uint2* __restrict__ stage,
        int N, int E, int B1){
    __shared__ int hist[1024];            // B1 <= 1024 (N <= 65536)
    int c = (int)blockIdx.x;
    int t = c / NPB, blk = c % NPB;
    const int* src = t ? src1 : src0;
    const int* dst = t ? dst1 : dst0;
    const float* ew = t ? ew1 : ew0;
    uint2* stg = stage + (size_t)t * B1 * CAPB;
    const int* co = cnts + (size_t)(t * NPB + blk) * B1;
    const int tid = threadIdx.x;
    for (int i = tid; i < B1; i += 256) hist[i] = co[i];
    __syncthreads();
    int per = (E + NPB - 1) / NPB;
    int e0 = blk * per;
    int e1 = e0 + per; if (e1 > E) e1 = E;
    for (int e = e0 + tid; e < e1; e += 256 * EPT){
        int dl[EPT], sl[EPT]; float wl[EPT];
        #pragma unroll
        for (int q = 0; q < EPT; ++q){
            int ee = e + q*256;
            if (ee < e1){ dl[q] = dst[ee]; sl[q] = src[ee]; wl[q] = fmaxf(ew[ee], 0.f); }
            else dl[q] = -1;
        }
        int r[EPT];
        #pragma unroll
        for (int q = 0; q < EPT; ++q)
            if (dl[q] >= 0) r[q] = atomicAdd(&hist[dl[q] >> BSH], 1);
        #pragma unroll
        for (int q = 0; q < EPT; ++q)
            if (dl[q] >= 0 && r[q] < CAPB)
                stg[(size_t)(dl[q] >> BSH) * CAPB + r[q]] =
                    make_uint2(__float_as_uint(wl[q]),
                               (unsigned)sl[q] | ((unsigned)(dl[q] & 63) << 16));
    }
}

// ===== pack: per-bucket 64-bin count+scan -> woff, sn (CSR, w as half2),
//       dinv, and fused dinv-prescale of this bucket's h1 rows =====
__global__ void __launch_bounds__(256) k_pack(const uint2* __restrict__ stage,
        const int* __restrict__ gcnt, int* __restrict__ woff,
        uint2* __restrict__ sn, float* __restrict__ dinv,
        __half* __restrict__ h1, int N, int E, int B1){
    const int bid = (int)blockIdx.x, tid = threadIdx.x;
    const int t = bid / B1, b = bid % B1;
    const uint2* stg = stage + (size_t)t * B1 * CAPB;
    const int* gc = gcnt + t * B1;
    __shared__ int   wsum[4];
    __shared__ int   nh[64];
    __shared__ float nw[64];
    __shared__ int   offs[64];
    __shared__ float dvs[64];
    // exclusive bucket base = sum gc[0..b)
    int acc = 0;
    for (int i = tid; i < b; i += 256) acc += gc[i];
    #pragma unroll
    for (int o = 32; o; o >>= 1) acc += __shfl_down(acc, o);
    int lane = tid & 63, wv = tid >> 6;
    if (lane == 0) wsum[wv] = acc;
    if (tid < 64){ nh[tid] = 0; nw[tid] = 0.f; }
    __syncthreads();
    const int base = wsum[0] + wsum[1] + wsum[2] + wsum[3];
    int cnt = gc[b]; if (cnt > CAPB) cnt = CAPB;

    int   rr[7]; uint2 rec[7];
    #pragma unroll
    for (int q = 0; q < 7; ++q){
        int j = q * 256 + tid;
        if (j < cnt){
            uint2 v = stg[(size_t)b * CAPB + j];
            int nl = (v.y >> 16) & 63;
            rr[q] = atomicAdd(&nh[nl], 1);
            atomicAdd(&nw[nl], __uint_as_float(v.x));
            rec[q] = v;
        } else rec[q].y = 0xFFFFFFFFu;     // real records have bits 22..31 == 0
    }
    __syncthreads();
    if (tid < 64){
        int v = nh[tid], sc = v;
        #pragma unroll
        for (int o = 1; o < 64; o <<= 1){ int u = __shfl_up(sc, o); if (tid >= o) sc += u; }
        offs[tid] = sc - v;                // exclusive within-bucket prefix
        int n = (b << BSH) + tid;
        float dv = 0.f;
        if (n < N){
            dv = rsqrtf(FILLW + nw[tid]);
            woff[t * N + n] = base + sc - v;
            dinv[t * N + n] = dv;
        }
        dvs[tid] = dv;
    }
    __syncthreads();
    uint2* sno = sn + (size_t)t * E;
    #pragma unroll
    for (int q = 0; q < 7; ++q){
        if (rec[q].y != 0xFFFFFFFFu){
            int nl   = (int)((rec[q].y >> 16) & 63);
            unsigned srcv = rec[q].y & 0xFFFFu;
            __half hw = __float2half(__uint_as_float(rec[q].x));
            unsigned hu = (unsigned)__half_as_ushort(hw);
            sno[(size_t)base + offs[nl] + rr[q]] =
                make_uint2(srcv, hu | (hu << 16));
        }
    }
    // fused prescale: h1 rows of this bucket *= dinv (64 rows x 64 halves)
    __half2* hb = (__half2*)(h1 + ((size_t)t * N + ((size_t)b << BSH)) * 64);
    #pragma unroll
    for (int j = 0; j < 8; ++j){
        int idx = j * 256 + tid;
        int r = idx >> 5, cc = idx & 31;
        if ((b << BSH) + r < N){
            float2 f = __half22float2(hb[r * 32 + cc]);
            float dv = dvs[r];
            hb[r * 32 + cc] = __floats2half2_rn(f.x * dv, f.y * dv);
        }
    }
}

// ================== GEMM2: fp32 in, dinv-prescaled fp16 out ==================
__global__ void __launch_bounds__(256) k_gemm2(const float* __restrict__ A0,
        const float* __restrict__ A1, const float* __restrict__ W,
        __half* __restrict__ C0, __half* __restrict__ C1,
        const float* __restrict__ dinv, int N, int BPT){
    __shared__ float Ws[64 * 128];
    __shared__ float As[2 * 16 * 132];
    int t  = (int)blockIdx.x / BPT;
    int rb = ((int)blockIdx.x - t * BPT) * 128;
    gemm_tile<128,64,128,16,true,__half>(t ? A1 : A0, W, t ? C1 : C0,
                                         dinv + t * N, rb, N, Ws, As);
}

// ===== CSR gather-max, grouped-row geometry + packed-f16 math =====
// LPR = F/8 lanes per row (16B/lane); EG = 64/LPR rows per wave-load; UG
// groups unrolled. Out-of-range slots clamp to edge m-1 (idempotent).
// Math: acc/products kept as packed half2 words (v_pk_mul/v_pk_max).
template<int F, int UG>
__global__ void __launch_bounds__(256) k_agg(const int* __restrict__ woff,
        const uint2* __restrict__ sn, const float* __restrict__ dinv,
        const __half* __restrict__ H0, const __half* __restrict__ H1,
        const float* __restrict__ bias, float* __restrict__ O0, float* __restrict__ O1,
        int N, int E, int BPT){
    constexpr int LPR = F / 8;        // lanes per row
    constexpr int EG  = 64 / LPR;     // edges per group
    const int t = (int)blockIdx.x / BPT;
    const int lane = threadIdx.x & 63, wv = threadIdx.x >> 6;
    int n = ((int)blockIdx.x - t * BPT) * 4 + wv;
    if (n >= N) return;
    int g = t * N + n;
    int beg = woff[g];
    int end = (n == N - 1) ? E : woff[g + 1];
    int cnt = end - beg;
    const uint2* st = sn + (size_t)t * E;
    const __half* H = t ? H1 : H0;
    float* O = t ? O1 : O0;
    const int fl = lane % LPR;
    const int eg = lane / LPR;

    unsigned acc[4];
    {
        float4 hv = *(const float4*)(H + (size_t)n * F + fl * 8);
        const unsigned* hp = (const unsigned*)&hv;
        const unsigned two2 = 0x40004000u;       // half2(2.0, 2.0)
        #pragma unroll
        for (int k = 0; k < 4; ++k) acc[k] = pk_mul(hp[k], two2);
    }
    for (int base = 0; base < cnt; base += 64){
        int m = cnt - base; if (m > 64) m = 64;
        uint2 er = make_uint2(0u, 0u);
        if (lane < m) er = st[beg + base + lane];     // ONE coalesced load: 64 records
        int es = (int)er.x;                            // src
        int ep = (int)er.y;                            // half2(w,w) bits
        for (int j = 0; j < m; j += EG * UG){
            int sl[UG], wl[UG]; float4 hv[UG];
            #pragma unroll
            for (int u = 0; u < UG; ++u){
                int jj = j + u * EG + eg; if (jj > m - 1) jj = m - 1;
                sl[u] = __shfl(es, jj);
                wl[u] = __shfl(ep, jj);
            }
            #pragma unroll
            for (int u = 0; u < UG; ++u)
                hv[u] = *(const float4*)(H + (size_t)sl[u] * F + fl * 8);
            #pragma unroll
            for (int u = 0; u < UG; ++u){
                const unsigned* hp = (const unsigned*)&hv[u];
                unsigned w2 = (unsigned)wl[u];
                #pragma unroll
                for (int k = 0; k < 4; ++k)
                    acc[k] = pk_max(acc[k], pk_mul(hp[k], w2));
            }
        }
    }
    #pragma unroll
    for (int msk = LPR; msk < 64; msk <<= 1)
        #pragma unroll
        for (int k = 0; k < 4; ++k){
            unsigned o = (unsigned)__shfl_xor((int)acc[k], msk);
            acc[k] = pk_max(acc[k], o);
        }
    float di = dinv[g];
    if constexpr (F == 128){
        int f0 = fl * 8 + eg * 2;
        float2 f = __half22float2(*(__half2*)&acc[eg]);
        float2 bb = *(const float2*)(bias + f0);
        *(float2*)(O + (size_t)n * F + f0) =
            make_float2(di * f.x + bb.x, di * f.y + bb.y);
    } else {
        int f0 = fl * 8 + eg;
        unsigned av = acc[eg >> 1];
        unsigned short hs = (unsigned short)((eg & 1) ? (av >> 16) : (av & 0xFFFFu));
        float v = __half2float(__ushort_as_half(hs));
        O[(size_t)n * F + f0] = di * v + bias[f0];
    }
}

// ============================== host ==============================

extern "C" void kernel_launch(void* const* d_in, const int* in_sizes, int n_in,
                              void* d_out, int out_size, void* d_ws, size_t ws_size,
                              hipStream_t stream){
    const int E  = in_sizes[2];        // 800000
    const int F1 = in_sizes[7];        // 64
    const int F2 = in_sizes[9];        // 128
    const int IN = in_sizes[6] / F1;   // 128
    const int N  = in_sizes[0] / IN;   // 50000 (< 65536 for 8B staging records)
    const int B1 = (N + 63) >> BSH;    // 782 coarse buckets

    const float* W1 = (const float*)d_in[6];
    const float* b1 = (const float*)d_in[7];
    const float* W2 = (const float*)d_in[8];
    const float* b2 = (const float*)d_in[9];

    auto need = [&](int G){
        return (size_t)G * E * 8              // sn (uint2)
             + (size_t)G * N * F2 * 2         // hbuf (fp16)
             + (size_t)G * N * F1 * 4         // out1 (stage aliases: G*B1*CAPB*8 <= this)
             + (size_t)G * N * 8              // dinv + woff
             + (size_t)G * B1 * 4             // gcnt
             + (size_t)G * NPB * B1 * 4       // cnts
             + 4096;
    };
    const int G = (ws_size >= need(2)) ? 2 : 1;

    uint2*  sn    = (uint2*)d_ws;
    __half* hbuf  = (__half*)(sn + (size_t)G * E);
    float*  out1  = (float*)(hbuf + (size_t)G * N * F2);
    uint2*  stage = (uint2*)out1;              // G*B1*CAPB*8B = 22.4MB <= 25.6MB
    float*  dinv  = out1 + (size_t)G * N * F1;
    int*    woff  = (int*)(dinv + (size_t)G * N);
    int*    gcnt  = woff + (size_t)G * N;
    int*    cnts  = gcnt + (size_t)G * B1;

    const int BPT1 = (N + 255) / 256;
    const int BPT2 = (N + 127) / 128;
    const int ABT  = (N + 3) / 4;
    const int GB   = G * BPT1;

    for (int it = 0; it < 2; it += G){
        int t0 = it, t1 = (G == 2) ? it + 1 : it;
        const float* x0 = (const float*)d_in[t0*3], * x1 = (const float*)d_in[t1*3];
        const int* ei0 = (const int*)d_in[t0*3+1], * ei1 = (const int*)d_in[t1*3+1];
        const float* ew0 = (const float*)d_in[t0*3+2], * ew1 = (const float*)d_in[t1*3+2];
        const int* src0 = ei0, * dst0 = ei0 + E;
        const int* src1 = ei1, * dst1 = ei1 + E;
        __half* h1_0 = hbuf, * h1_1 = hbuf + (size_t)(G-1) * N * F1;
        __half* h2_0 = hbuf, * h2_1 = hbuf + (size_t)(G-1) * N * F2;
        float* o1_0 = out1, * o1_1 = out1 + (size_t)(G-1) * N * F1;
        float* go0 = (float*)d_out + (size_t)t0 * N * F2;
        float* go1 = (float*)d_out + (size_t)t1 * N * F2;

        k_cg1<<<GB + G * NPB, 256, 0, stream>>>(x0, x1, W1, h1_0, h1_1,
                                                dst0, dst1, cnts, N, E, BPT1, GB, B1);
        k_scanR<<<G * B1, 64, 0, stream>>>(cnts, gcnt, B1);
        k_scatter<<<G * NPB, 256, 0, stream>>>(src0, src1, dst0, dst1, ew0, ew1,
                                               cnts, stage, N, E, B1);
        k_pack<<<G * B1, 256, 0, stream>>>(stage, gcnt, woff, sn, dinv, hbuf, N, E, B1);
        k_agg<64,4><<<G * ABT, 256, 0, stream>>>(woff, sn, dinv, h1_0, h1_1, b1,
                                                 o1_0, o1_1, N, E, ABT);
        k_gemm2<<<G * BPT2, 256, 0, stream>>>(o1_0, o1_1, W2, h2_0, h2_1, dinv, N, BPT2);
        k_agg<128,4><<<G * ABT, 256, 0, stream>>>(woff, sn, dinv, h2_0, h2_1, b2,
                                                  go0, go1, N, E, ABT);
    }
}